// Round 9
// baseline (463.450 us; speedup 1.0000x reference)
//
#include <hip/hip_runtime.h>
#include <cstdint>

using u16 = unsigned short;
using u32 = unsigned int;
typedef __attribute__((ext_vector_type(4))) float f32x4;
typedef __attribute__((ext_vector_type(8))) short short8;
typedef __attribute__((ext_vector_type(4))) u16 u16x4;
typedef __attribute__((ext_vector_type(8))) u16 u16x8;

// ---------- helpers ----------
__device__ __forceinline__ u16 f2bf(float f) {
  u32 u = __builtin_bit_cast(u32, f);
  u += 0x7FFFu + ((u >> 16) & 1u);
  return (u16)(u >> 16);
}
__device__ __forceinline__ float bf2f(u16 x) {
  return __builtin_bit_cast(float, (u32)x << 16);
}

__device__ __forceinline__ void gload16(const void* g, void* l) {
  __builtin_amdgcn_global_load_lds(
      (const __attribute__((address_space(1))) void*)g,
      (__attribute__((address_space(3))) void*)l, 16, 0, 0);
}

__device__ __forceinline__ float fast_tanh(float x) {
  float ax = fabsf(x);
  float e = __expf(-2.0f * ax);
  float r = (1.0f - e) / (1.0f + e);
  return x < 0.0f ? -r : r;
}

#define SBAR() do { asm volatile("" ::: "memory"); __builtin_amdgcn_s_barrier(); asm volatile("" ::: "memory"); } while (0)

template<int N> __device__ __forceinline__ void vmw() {
  if constexpr (N == 10) asm volatile("s_waitcnt vmcnt(10)" ::: "memory");
  else if constexpr (N == 8) asm volatile("s_waitcnt vmcnt(8)" ::: "memory");
  else if constexpr (N == 6) asm volatile("s_waitcnt vmcnt(6)" ::: "memory");
  else if constexpr (N == 4) asm volatile("s_waitcnt vmcnt(4)" ::: "memory");
  else if constexpr (N == 2) asm volatile("s_waitcnt vmcnt(2)" ::: "memory");
  else if constexpr (N == 0) asm volatile("s_waitcnt vmcnt(0)" ::: "memory");
  // N == -1: no wait
}

// st_16x32 XOR swizzle on a byte offset within a 16 KiB half-tile
__device__ __forceinline__ int swz(int L) { return L ^ (((L >> 9) & 1) << 5); }

// XCD-aware swizzle for 512 blocks (128 m-tiles x 4 n-tiles of 256)
__device__ __forceinline__ void swz_mn256(int bid, int& m0, int& n0) {
  int s = (bid & 7) * 64 + (bid >> 3);
  n0 = (s & 3) << 8;
  m0 = (s >> 2) << 8;
}

// ---------- fp32 -> bf16 convert ----------
__global__ void cvt_ker(const float4* __restrict__ src, u16x4* __restrict__ dst, int n4) {
  int i = blockIdx.x * 256 + threadIdx.x;
  if (i < n4) {
    float4 f = src[i];
    u16x4 o = { f2bf(f.x), f2bf(f.y), f2bf(f.z), f2bf(f.w) };
    dst[i] = o;
  }
}

// ---------- 256x256 GEMM mainloop, BK=64, SW-PIPELINED ds_reads, vmcnt ONCE/K-tile ----------
// C[m][n] += sum_k A[m][k]*B[n][k], A/B bf16 row-major (BT form), K tiles of 64.
// 512 threads = 8 waves (2 wr x 4 wc); per-wave C 128x64 = acc[8][4] of 16x16.
// LDS 128 KiB: [buf:2][half:4][8192 elems]; half 0=B.kk0 1=A.kk0 2=B.kk1 3=A.kk1.
// Stage stream S[j] (jt=j>>2, hh=j&3): prologue stages S[0..6]; phase G stages S[G+7].
// Reads pipelined one phase ahead; compiler-counted lgkmcnt covers them.
// vmcnt LEDGER (the only vmcnt is at each tile's P3):
//   vmcnt(4) @ end of phase 4t+3 -> all but last 2 stage_halfs done -> S[<=4t+8] complete.
//   tile t+1 reads S[4t+5..4t+7]; its P3 pre-read touches S[4t+8]  -> exactly covered.
//   tile 0 peeled with waits (8,-1,8,4); tile NT-2 ends vmcnt(0); tile NT-1 waits nothing.
__device__ __forceinline__ void stage_half(
    const u16* __restrict__ A0, const u16* __restrict__ B0,
    const u16* __restrict__ A1, const u16* __restrict__ B1,
    int half_nt, u16* lds, int j, int m0, int n0, int w, int rc0, int rc1)
{
  int jt = j >> 2, hh = j & 3;
  int kk = hh >> 1, isA = hh & 1;
  const u16* src;
  int kt;
  if (jt < half_nt) { src = isA ? A0 : B0; kt = jt; }
  else              { src = isA ? A1 : B1; kt = jt - half_nt; }
  int base_row = isA ? m0 : n0;
  int koff = kt * 64 + kk * 32;
  u16* dst = lds + ((jt & 1) * 4 + hh) * 8192 + w * 512;
  const u16* g0 = src + (size_t)base_row * 1024 + koff;
  gload16(g0 + rc0, dst);
  gload16(g0 + rc1, dst + 4096);
}

__device__ __forceinline__ void rdB4(short8* d, const u16* lds, int buf, int kk, const int* boff) {
  const char* h = (const char*)(lds + (buf * 4 + kk * 2) * 8192);
  d[0] = *(const short8*)(h + boff[0]);
  d[1] = *(const short8*)(h + boff[1]);
  d[2] = *(const short8*)(h + boff[2]);
  d[3] = *(const short8*)(h + boff[3]);
}
__device__ __forceinline__ void rdA4(short8* d, const u16* lds, int buf, int kk, int mh, const int* aoff) {
  const char* h = (const char*)(lds + (buf * 4 + 1 + kk * 2) * 8192);
  d[0] = *(const short8*)(h + aoff[mh * 4 + 0]);
  d[1] = *(const short8*)(h + aoff[mh * 4 + 1]);
  d[2] = *(const short8*)(h + aoff[mh * 4 + 2]);
  d[3] = *(const short8*)(h + aoff[mh * 4 + 3]);
}

#define MFMA16(AS, BS, BASE) do {                                                   \
  __builtin_amdgcn_s_setprio(1);                                                    \
  _Pragma("unroll")                                                                 \
  for (int ni_ = 0; ni_ < 4; ni_++) {                                               \
    acc[(BASE)+0][ni_] = __builtin_amdgcn_mfma_f32_16x16x32_bf16(AS[0], BS[ni_], acc[(BASE)+0][ni_], 0, 0, 0); \
    acc[(BASE)+1][ni_] = __builtin_amdgcn_mfma_f32_16x16x32_bf16(AS[1], BS[ni_], acc[(BASE)+1][ni_], 0, 0, 0); \
    acc[(BASE)+2][ni_] = __builtin_amdgcn_mfma_f32_16x16x32_bf16(AS[2], BS[ni_], acc[(BASE)+2][ni_], 0, 0, 0); \
    acc[(BASE)+3][ni_] = __builtin_amdgcn_mfma_f32_16x16x32_bf16(AS[3], BS[ni_], acc[(BASE)+3][ni_], 0, 0, 0); \
  }                                                                                 \
  __builtin_amdgcn_s_setprio(0);                                                    \
} while (0)

// One K-tile = 4 phases. Phase: [reads for next phase][stage][MFMA(cur)][vmcnt?][bar]
#define TILE(T, V0, V1, V2, V3, S0_, S1_, S2_, S3_, NX) do {                        \
  const int buf_ = (T) & 1;                                                         \
  /* P0: mfma(kk0,mh0) on a0s,b0s; read a1s = A.mh1.kk0 */                          \
  rdA4(a1s, lds, buf_, 0, 1, aoff);                                                 \
  if (S0_) stage_half(A0, B0, A1, B1, half_nt, lds, 4 * (T) + 7, m0, n0, w, rc0, rc1); \
  MFMA16(a0s, b0s, 0);                                                              \
  vmw<V0>(); SBAR();                                                                \
  /* P1: mfma(kk0,mh1) on a1s,b0s; read b1s = B.kk1, a0s = A.mh0.kk1 */             \
  rdB4(b1s, lds, buf_, 1, boff);                                                    \
  rdA4(a0s, lds, buf_, 1, 0, aoff);                                                 \
  if (S1_) stage_half(A0, B0, A1, B1, half_nt, lds, 4 * (T) + 8, m0, n0, w, rc0, rc1); \
  MFMA16(a1s, b0s, 4);                                                              \
  vmw<V1>(); SBAR();                                                                \
  /* P2: mfma(kk1,mh0) on a0s,b1s; read a1s = A.mh1.kk1 */                          \
  rdA4(a1s, lds, buf_, 1, 1, aoff);                                                 \
  if (S2_) stage_half(A0, B0, A1, B1, half_nt, lds, 4 * (T) + 9, m0, n0, w, rc0, rc1); \
  MFMA16(a0s, b1s, 0);                                                              \
  vmw<V2>(); SBAR();                                                                \
  /* P3: mfma(kk1,mh1) on a1s,b1s; read next tile's b0s = B.kk0, a0s = A.mh0.kk0 */ \
  if (NX) { rdB4(b0s, lds, buf_ ^ 1, 0, boff); rdA4(a0s, lds, buf_ ^ 1, 0, 0, aoff); } \
  if (S3_) stage_half(A0, B0, A1, B1, half_nt, lds, 4 * (T) + 10, m0, n0, w, rc0, rc1); \
  MFMA16(a1s, b1s, 4);                                                              \
  vmw<V3>(); SBAR();                                                                \
} while (0)

__device__ __forceinline__ void gemm_loop(
    const u16* __restrict__ A0, const u16* __restrict__ B0,
    const u16* __restrict__ A1, const u16* __restrict__ B1,
    int half_nt, int NT, int m0, int n0, u16* lds, f32x4 acc[8][4])
{
  const int tid = threadIdx.x;
  const int w = tid >> 6, lane = tid & 63;
  const int wr = w >> 2, wc = w & 3;
  const int lr = lane & 15, g = lane >> 4;

  // per-thread inverse-swizzled global (row*1024+col) offsets for the 2 stage insts
  int rc0, rc1;
  {
    int seg0 = w * 64 + lane, seg1 = 512 + w * 64 + lane;
    int L0 = swz(seg0 * 16), L1 = swz(seg1 * 16);
    rc0 = (L0 >> 6) * 1024 + ((L0 & 63) >> 1);
    rc1 = (L1 >> 6) * 1024 + ((L1 & 63) >> 1);
  }
  // swizzled ds_read byte offsets within a half
  int aoff[8], boff[4];
  #pragma unroll
  for (int mi = 0; mi < 8; mi++)
    aoff[mi] = swz((wr * 128 + mi * 16 + lr) * 64 + g * 16);
  #pragma unroll
  for (int ni = 0; ni < 4; ni++)
    boff[ni] = swz((wc * 64 + ni * 16 + lr) * 64 + g * 16);

  short8 a0s[4], a1s[4], b0s[4], b1s[4];

  // prologue: stage S[0..6]; vmcnt(10) confirms S0,S1; barrier; pre-read tile0 p0 frags
  #pragma unroll
  for (int j = 0; j < 7; j++)
    stage_half(A0, B0, A1, B1, half_nt, lds, j, m0, n0, w, rc0, rc1);
  vmw<10>();
  SBAR();
  rdB4(b0s, lds, 0, 0, boff);
  rdA4(a0s, lds, 0, 0, 0, aoff);

  // tile 0: extra waits while the prologue queue drains
  TILE(0, 8, -1, 8, 4, 1, 1, 1, 1, true);
  for (int t = 1; t < NT - 2; ++t)
    TILE(t, -1, -1, -1, 4, 1, 1, 1, 1, true);
  TILE(NT - 2, -1, -1, -1, 0, 1, 0, 0, 0, true);
  TILE(NT - 1, -1, -1, -1, -1, 0, 0, 0, 0, false);
}

// ---------- GEMM1: h = tanh(Q@W1^T + V@W2^T + b1 + b2), bf16 out ----------
__global__ void __launch_bounds__(512, 2)
gemm1_ker(const u16* __restrict__ q, const u16* __restrict__ v,
          const u16* __restrict__ w1, const u16* __restrict__ w2,
          const float* __restrict__ b1, const float* __restrict__ b2,
          u16* __restrict__ H)
{
  __shared__ u16 lds[65536];
  int m0, n0;
  swz_mn256(blockIdx.x, m0, n0);
  f32x4 acc[8][4];
  #pragma unroll
  for (int mi = 0; mi < 8; mi++)
    #pragma unroll
    for (int ni = 0; ni < 4; ni++) acc[mi][ni] = (f32x4){0.f, 0.f, 0.f, 0.f};

  gemm_loop(q, w1, v, w2, 16, 32, m0, n0, lds, acc);

  int tid = threadIdx.x, w = tid >> 6, lane = tid & 63;
  int wr = w >> 2, wc = w & 3, lr = lane & 15, g = lane >> 4;
  #pragma unroll
  for (int ni = 0; ni < 4; ni++) {
    int col = n0 + wc * 64 + ni * 16 + lr;
    float bias = b1[col] + b2[col];
    #pragma unroll
    for (int mi = 0; mi < 8; mi++)
      #pragma unroll
      for (int r = 0; r < 4; r++) {
        int row = m0 + wr * 128 + mi * 16 + g * 4 + r;
        H[(size_t)row * 1024 + col] = f2bf(fast_tanh(acc[mi][ni][r] + bias));
      }
  }
}

// ---------- escore: e = exp(h@Vw^T + vb) -> e_bf16 + per-(nblk,row) partial sums ----------
__global__ void __launch_bounds__(512, 2)
escore_ker(const u16* __restrict__ h, const u16* __restrict__ vw,
           const float* __restrict__ vb, u16* __restrict__ E,
           float* __restrict__ partial)
{
  __shared__ u16 lds[65536];
  int m0, n0;
  swz_mn256(blockIdx.x, m0, n0);
  f32x4 acc[8][4];
  #pragma unroll
  for (int mi = 0; mi < 8; mi++)
    #pragma unroll
    for (int ni = 0; ni < 4; ni++) acc[mi][ni] = (f32x4){0.f, 0.f, 0.f, 0.f};

  gemm_loop(h, vw, h, vw, 16, 16, m0, n0, lds, acc);

  int tid = threadIdx.x, w = tid >> 6, lane = tid & 63;
  int wr = w >> 2, wc = w & 3, lr = lane & 15, g = lane >> 4;

  // e = exp(score + vb); |score| bounded ~17 so no max-subtraction needed (fp32 safe)
  #pragma unroll
  for (int ni = 0; ni < 4; ni++) {
    float vbc = vb[n0 + wc * 64 + ni * 16 + lr];
    #pragma unroll
    for (int mi = 0; mi < 8; mi++)
      #pragma unroll
      for (int r = 0; r < 4; r++)
        acc[mi][ni][r] = __expf(acc[mi][ni][r] + vbc);
  }

  // per-(nblk,row) partial sums: reduce ni in-reg, lr via shfl, wc via LDS
  __syncthreads();            // all loop LDS traffic done before reuse as ps
  float* ps = (float*)lds;    // [wc:4][row:256], unique writer per slot
  #pragma unroll
  for (int mi = 0; mi < 8; mi++) {
    #pragma unroll
    for (int r = 0; r < 4; r++) {
      float t = acc[mi][0][r] + acc[mi][1][r] + acc[mi][2][r] + acc[mi][3][r];
      t += __shfl_xor(t, 1, 64);
      t += __shfl_xor(t, 2, 64);
      t += __shfl_xor(t, 4, 64);
      t += __shfl_xor(t, 8, 64);
      if (lr == 0) ps[wc * 256 + wr * 128 + mi * 16 + g * 4 + r] = t;
    }
  }
  __syncthreads();
  if (tid < 256) {
    float s = ps[tid] + ps[256 + tid] + ps[512 + tid] + ps[768 + tid];
    partial[(size_t)(n0 >> 8) * 32768 + m0 + tid] = s;
  }

  // e -> bf16 direct scatter stores
  #pragma unroll
  for (int ni = 0; ni < 4; ni++) {
    int col = n0 + wc * 64 + ni * 16 + lr;
    #pragma unroll
    for (int mi = 0; mi < 8; mi++)
      #pragma unroll
      for (int r = 0; r < 4; r++) {
        int row = m0 + wr * 128 + mi * 16 + g * 4 + r;
        E[(size_t)row * 1024 + col] = f2bf(acc[mi][ni][r]);
      }
  }
}

// ---------- rowsum: inv[row] = 1/sum of 4 n-block partials ----------
__global__ void rowsum_ker(const float* __restrict__ partial, float* __restrict__ inv) {
  int r = blockIdx.x * 256 + threadIdx.x;
  float s = partial[r] + partial[32768 + r] + partial[65536 + r] + partial[98304 + r];
  inv[r] = 1.0f / s;
}

// ---------- transpose v_bf per batch: [b][l][h] -> [b][h][l] ----------
__global__ void transpose_ker(const u16* __restrict__ in, u16* __restrict__ out) {
  __shared__ u16 tile[64][68];
  int b = blockIdx.z;
  int h0 = blockIdx.x * 64, l0 = blockIdx.y * 64;
  const u16* src = in + (size_t)b * 1048576;
  u16* dst = out + (size_t)b * 1048576;
  int t = threadIdx.x;
  #pragma unroll
  for (int i = 0; i < 4; i++) {
    int idx = i * 1024 + t * 4;
    int r = idx >> 6, c = idx & 63;
    *(u16x4*)&tile[r][c] = *(const u16x4*)&src[(size_t)(l0 + r) * 1024 + h0 + c];
  }
  __syncthreads();
  #pragma unroll
  for (int i = 0; i < 4; i++) {
    int idx = i * 1024 + t * 4;
    int hr = idx >> 6, lc = idx & 63;
    u16x4 val = { tile[lc][hr], tile[lc + 1][hr], tile[lc + 2][hr], tile[lc + 3][hr] };
    *(u16x4*)&dst[(size_t)(h0 + hr) * 1024 + l0 + lc] = val;
  }
}

// ---------- GEMM3: context[b] = (e[b] @ value[b]) * inv[row]; fused out_w quarter ----------
__global__ void __launch_bounds__(512, 2)
gemm3_ker(const u16* __restrict__ E, const u16* __restrict__ vT,
          const float* __restrict__ inv, float* __restrict__ ctx,
          float* __restrict__ out_w)
{
  __shared__ u16 lds[65536];
  int m0, n0;
  swz_mn256(blockIdx.x, m0, n0);
  const u16* Bb = vT + (size_t)(m0 >> 10) * 1048576;   // 256 | 1024: tile never straddles batches
  f32x4 acc[8][4];
  #pragma unroll
  for (int mi = 0; mi < 8; mi++)
    #pragma unroll
    for (int ni = 0; ni < 4; ni++) acc[mi][ni] = (f32x4){0.f, 0.f, 0.f, 0.f};

  gemm_loop(E, Bb, E, Bb, 16, 16, m0, n0, lds, acc);

  int tid = threadIdx.x, w = tid >> 6, lane = tid & 63;
  int wr = w >> 2, wc = w & 3, lr = lane & 15, g = lane >> 4;
  #pragma unroll
  for (int mi = 0; mi < 8; mi++) {
    #pragma unroll
    for (int r = 0; r < 4; r++) {
      int row = m0 + wr * 128 + mi * 16 + g * 4 + r;
      float sc = inv[row];
      #pragma unroll
      for (int ni = 0; ni < 4; ni++) {
        int col = n0 + wc * 64 + ni * 16 + lr;
        ctx[(size_t)row * 1024 + col] = acc[mi][ni][r] * sc;
      }
    }
  }

  // fused wout: out_w[m0..+255][n0..+255] = bf2f(E)*inv. Disjoint quarters across
  // blocks (full cover, no overlap). Per iter: 512 thr x 64B cells, fully coalesced.
  #pragma unroll
  for (int i = 0; i < 8; i++) {
    int row = i * 32 + (tid >> 4);
    int col = (tid & 15) * 16;
    const u16* es = E + (size_t)(m0 + row) * 1024 + n0 + col;
    float* wd = out_w + (size_t)(m0 + row) * 1024 + n0 + col;
    float sc = inv[m0 + row];
    u16x8 v0 = *(const u16x8*)es;
    u16x8 v1 = *(const u16x8*)(es + 8);
    float4 o;
    o.x = bf2f(v0[0]) * sc; o.y = bf2f(v0[1]) * sc; o.z = bf2f(v0[2]) * sc; o.w = bf2f(v0[3]) * sc;
    *(float4*)wd = o;
    o.x = bf2f(v0[4]) * sc; o.y = bf2f(v0[5]) * sc; o.z = bf2f(v0[6]) * sc; o.w = bf2f(v0[7]) * sc;
    *(float4*)(wd + 4) = o;
    o.x = bf2f(v1[0]) * sc; o.y = bf2f(v1[1]) * sc; o.z = bf2f(v1[2]) * sc; o.w = bf2f(v1[3]) * sc;
    *(float4*)(wd + 8) = o;
    o.x = bf2f(v1[4]) * sc; o.y = bf2f(v1[5]) * sc; o.z = bf2f(v1[6]) * sc; o.w = bf2f(v1[7]) * sc;
    *(float4*)(wd + 12) = o;
  }
}

// ---------- launch ----------
extern "C" void kernel_launch(void* const* d_in, const int* in_sizes, int n_in,
                              void* d_out, int out_size, void* d_ws, size_t ws_size,
                              hipStream_t stream) {
  const float* q   = (const float*)d_in[0];
  // d_in[1] = key, unused by reference
  const float* v   = (const float*)d_in[2];
  const float* w1w = (const float*)d_in[3];
  const float* b1  = (const float*)d_in[4];
  const float* w2w = (const float*)d_in[5];
  const float* b2  = (const float*)d_in[6];
  const float* vww = (const float*)d_in[7];
  const float* vb  = (const float*)d_in[8];

  float* out_w = (float*)d_out;                 // attention_weights (32,1024,1024) fp32
  float* out_c = out_w + (size_t)33554432;      // context          (32,1024,1024) fp32

  u16* q_bf  = (u16*)d_ws;
  u16* v_bf  = q_bf + 33554432;
  u16* h_bf  = v_bf + 33554432;
  u16* w1_bf = h_bf + 33554432;
  u16* w2_bf = w1_bf + 1048576;
  u16* vw_bf = w2_bf + 1048576;
  u16* wsm_bf = q_bf;                   // e bf16: reuse q region (dead after gemm1)
  u16* vT_bf  = h_bf;                   // transposed V: reuse h region (dead after escore)
  float* partial = (float*)w1_bf;       // 512 KB (w1 dead after gemm1)
  float* invp    = (float*)w2_bf;       // 128 KB (w2 dead after gemm1)

  if (ws_size < (size_t)207618048) return;

  cvt_ker<<<32768, 256, 0, stream>>>((const float4*)q,   (u16x4*)q_bf,  8388608);
  cvt_ker<<<32768, 256, 0, stream>>>((const float4*)v,   (u16x4*)v_bf,  8388608);
  cvt_ker<<<1024,  256, 0, stream>>>((const float4*)w1w, (u16x4*)w1_bf, 262144);
  cvt_ker<<<1024,  256, 0, stream>>>((const float4*)w2w, (u16x4*)w2_bf, 262144);
  cvt_ker<<<1024,  256, 0, stream>>>((const float4*)vww, (u16x4*)vw_bf, 262144);

  gemm1_ker<<<512, 512, 0, stream>>>(q_bf, v_bf, w1_bf, w2_bf, b1, b2, h_bf);
  escore_ker<<<512, 512, 0, stream>>>(h_bf, vw_bf, vb, wsm_bf, partial);
  rowsum_ker<<<128, 256, 0, stream>>>(partial, invp);
  transpose_ker<<<dim3(16, 16, 32), 256, 0, stream>>>(v_bf, vT_bf);
  gemm3_ker<<<512, 512, 0, stream>>>(wsm_bf, vT_bf, invp, out_c, out_w);
}

// Round 10
// 440.510 us; speedup vs baseline: 1.0521x; 1.0521x over previous
//
#include <hip/hip_runtime.h>
#include <cstdint>

using u16 = unsigned short;
using u32 = unsigned int;
typedef __attribute__((ext_vector_type(4))) float f32x4;
typedef __attribute__((ext_vector_type(8))) short short8;
typedef __attribute__((ext_vector_type(4))) u16 u16x4;
typedef __attribute__((ext_vector_type(8))) u16 u16x8;

// ---------- helpers ----------
__device__ __forceinline__ u16 f2bf(float f) {
  u32 u = __builtin_bit_cast(u32, f);
  u += 0x7FFFu + ((u >> 16) & 1u);
  return (u16)(u >> 16);
}
__device__ __forceinline__ float bf2f(u16 x) {
  return __builtin_bit_cast(float, (u32)x << 16);
}

__device__ __forceinline__ void gload16(const void* g, void* l) {
  __builtin_amdgcn_global_load_lds(
      (const __attribute__((address_space(1))) void*)g,
      (__attribute__((address_space(3))) void*)l, 16, 0, 0);
}

__device__ __forceinline__ float fast_tanh(float x) {
  float ax = fabsf(x);
  float e = __expf(-2.0f * ax);
  float r = (1.0f - e) / (1.0f + e);
  return x < 0.0f ? -r : r;
}

#define SBAR() do { asm volatile("" ::: "memory"); __builtin_amdgcn_s_barrier(); asm volatile("" ::: "memory"); } while (0)

template<int N> __device__ __forceinline__ void vmw() {
  if constexpr (N == 10) asm volatile("s_waitcnt vmcnt(10)" ::: "memory");
  else if constexpr (N == 8) asm volatile("s_waitcnt vmcnt(8)" ::: "memory");
  else if constexpr (N == 6) asm volatile("s_waitcnt vmcnt(6)" ::: "memory");
  else if constexpr (N == 4) asm volatile("s_waitcnt vmcnt(4)" ::: "memory");
  else if constexpr (N == 2) asm volatile("s_waitcnt vmcnt(2)" ::: "memory");
  else if constexpr (N == 0) asm volatile("s_waitcnt vmcnt(0)" ::: "memory");
  // N == -1: no wait
}

// st_16x32 XOR swizzle on a byte offset within a 16 KiB half-tile
__device__ __forceinline__ int swz(int L) { return L ^ (((L >> 9) & 1) << 5); }

// XCD-aware swizzle for 512 blocks (128 m-tiles x 4 n-tiles of 256)
__device__ __forceinline__ void swz_mn256(int bid, int& m0, int& n0) {
  int s = (bid & 7) * 64 + (bid >> 3);
  n0 = (s & 3) << 8;
  m0 = (s >> 2) << 8;
}

// ---------- fp32 -> bf16 convert ----------
__global__ void cvt_ker(const float4* __restrict__ src, u16x4* __restrict__ dst, int n4) {
  int i = blockIdx.x * 256 + threadIdx.x;
  if (i < n4) {
    float4 f = src[i];
    u16x4 o = { f2bf(f.x), f2bf(f.y), f2bf(f.z), f2bf(f.w) };
    dst[i] = o;
  }
}

// ---------- merged weight cvt: y selects among w1,w2,vw (each 1M f32) ----------
__global__ void wcvt_ker(const float4* __restrict__ w1, const float4* __restrict__ w2,
                         const float4* __restrict__ vw, u16x4* __restrict__ d1,
                         u16x4* __restrict__ d2, u16x4* __restrict__ d3) {
  int i = blockIdx.x * 256 + threadIdx.x;   // 262144 float4 per matrix
  const float4* s = blockIdx.y == 0 ? w1 : blockIdx.y == 1 ? w2 : vw;
  u16x4* d = blockIdx.y == 0 ? d1 : blockIdx.y == 1 ? d2 : d3;
  float4 f = s[i];
  u16x4 o = { f2bf(f.x), f2bf(f.y), f2bf(f.z), f2bf(f.w) };
  d[i] = o;
}

// ---------- fused V cvt + transpose (big-ws path): f32 [b][l][h] -> bf16 [b][l][h] AND [b][h][l] ----------
__global__ void vcvtT_ker(const float* __restrict__ src, u16* __restrict__ v_bf,
                          u16* __restrict__ vT) {
  __shared__ u16 tile[64][68];   // 68: keeps u16x4 8B-aligned, breaks bank stride
  int b = blockIdx.z;
  int h0 = blockIdx.x * 64, l0 = blockIdx.y * 64;
  const float* s = src + (size_t)b * 1048576;
  u16* dv = v_bf + (size_t)b * 1048576;
  u16* dt = vT + (size_t)b * 1048576;
  int t = threadIdx.x;
  #pragma unroll
  for (int i = 0; i < 4; i++) {
    int idx = i * 1024 + t * 4;
    int r = idx >> 6, c = idx & 63;
    float4 f = *(const float4*)&s[(size_t)(l0 + r) * 1024 + h0 + c];
    tile[r][c] = f2bf(f.x); tile[r][c + 1] = f2bf(f.y);
    tile[r][c + 2] = f2bf(f.z); tile[r][c + 3] = f2bf(f.w);
  }
  __syncthreads();
  #pragma unroll
  for (int i = 0; i < 4; i++) {
    int idx = i * 1024 + t * 4;
    int r = idx >> 6, c = idx & 63;
    *(u16x4*)&dv[(size_t)(l0 + r) * 1024 + h0 + c] = *(const u16x4*)&tile[r][c];
  }
  #pragma unroll
  for (int i = 0; i < 4; i++) {
    int idx = i * 1024 + t * 4;
    int hr = idx >> 6, lc = idx & 63;
    u16x4 val = { tile[lc][hr], tile[lc + 1][hr], tile[lc + 2][hr], tile[lc + 3][hr] };
    *(u16x4*)&dt[(size_t)(h0 + hr) * 1024 + l0 + lc] = val;
  }
}

// ---------- 256x256 GEMM mainloop, BK=64, SW-PIPELINED ds_reads, vmcnt ONCE/K-tile ----------
// (structure measured r9: gemm1 158us / MfmaUtil 37.6% — best so far; unchanged this round)
__device__ __forceinline__ void stage_half(
    const u16* __restrict__ A0, const u16* __restrict__ B0,
    const u16* __restrict__ A1, const u16* __restrict__ B1,
    int half_nt, u16* lds, int j, int m0, int n0, int w, int rc0, int rc1)
{
  int jt = j >> 2, hh = j & 3;
  int kk = hh >> 1, isA = hh & 1;
  const u16* src;
  int kt;
  if (jt < half_nt) { src = isA ? A0 : B0; kt = jt; }
  else              { src = isA ? A1 : B1; kt = jt - half_nt; }
  int base_row = isA ? m0 : n0;
  int koff = kt * 64 + kk * 32;
  u16* dst = lds + ((jt & 1) * 4 + hh) * 8192 + w * 512;
  const u16* g0 = src + (size_t)base_row * 1024 + koff;
  gload16(g0 + rc0, dst);
  gload16(g0 + rc1, dst + 4096);
}

__device__ __forceinline__ void rdB4(short8* d, const u16* lds, int buf, int kk, const int* boff) {
  const char* h = (const char*)(lds + (buf * 4 + kk * 2) * 8192);
  d[0] = *(const short8*)(h + boff[0]);
  d[1] = *(const short8*)(h + boff[1]);
  d[2] = *(const short8*)(h + boff[2]);
  d[3] = *(const short8*)(h + boff[3]);
}
__device__ __forceinline__ void rdA4(short8* d, const u16* lds, int buf, int kk, int mh, const int* aoff) {
  const char* h = (const char*)(lds + (buf * 4 + 1 + kk * 2) * 8192);
  d[0] = *(const short8*)(h + aoff[mh * 4 + 0]);
  d[1] = *(const short8*)(h + aoff[mh * 4 + 1]);
  d[2] = *(const short8*)(h + aoff[mh * 4 + 2]);
  d[3] = *(const short8*)(h + aoff[mh * 4 + 3]);
}

#define MFMA16(AS, BS, BASE) do {                                                   \
  __builtin_amdgcn_s_setprio(1);                                                    \
  _Pragma("unroll")                                                                 \
  for (int ni_ = 0; ni_ < 4; ni_++) {                                               \
    acc[(BASE)+0][ni_] = __builtin_amdgcn_mfma_f32_16x16x32_bf16(AS[0], BS[ni_], acc[(BASE)+0][ni_], 0, 0, 0); \
    acc[(BASE)+1][ni_] = __builtin_amdgcn_mfma_f32_16x16x32_bf16(AS[1], BS[ni_], acc[(BASE)+1][ni_], 0, 0, 0); \
    acc[(BASE)+2][ni_] = __builtin_amdgcn_mfma_f32_16x16x32_bf16(AS[2], BS[ni_], acc[(BASE)+2][ni_], 0, 0, 0); \
    acc[(BASE)+3][ni_] = __builtin_amdgcn_mfma_f32_16x16x32_bf16(AS[3], BS[ni_], acc[(BASE)+3][ni_], 0, 0, 0); \
  }                                                                                 \
  __builtin_amdgcn_s_setprio(0);                                                    \
} while (0)

#define TILE(T, V0, V1, V2, V3, S0_, S1_, S2_, S3_, NX) do {                        \
  const int buf_ = (T) & 1;                                                         \
  rdA4(a1s, lds, buf_, 0, 1, aoff);                                                 \
  if (S0_) stage_half(A0, B0, A1, B1, half_nt, lds, 4 * (T) + 7, m0, n0, w, rc0, rc1); \
  MFMA16(a0s, b0s, 0);                                                              \
  vmw<V0>(); SBAR();                                                                \
  rdB4(b1s, lds, buf_, 1, boff);                                                    \
  rdA4(a0s, lds, buf_, 1, 0, aoff);                                                 \
  if (S1_) stage_half(A0, B0, A1, B1, half_nt, lds, 4 * (T) + 8, m0, n0, w, rc0, rc1); \
  MFMA16(a1s, b0s, 4);                                                              \
  vmw<V1>(); SBAR();                                                                \
  rdA4(a1s, lds, buf_, 1, 1, aoff);                                                 \
  if (S2_) stage_half(A0, B0, A1, B1, half_nt, lds, 4 * (T) + 9, m0, n0, w, rc0, rc1); \
  MFMA16(a0s, b1s, 0);                                                              \
  vmw<V2>(); SBAR();                                                                \
  if (NX) { rdB4(b0s, lds, buf_ ^ 1, 0, boff); rdA4(a0s, lds, buf_ ^ 1, 0, 0, aoff); } \
  if (S3_) stage_half(A0, B0, A1, B1, half_nt, lds, 4 * (T) + 10, m0, n0, w, rc0, rc1); \
  MFMA16(a1s, b1s, 4);                                                              \
  vmw<V3>(); SBAR();                                                                \
} while (0)

__device__ __forceinline__ void gemm_loop(
    const u16* __restrict__ A0, const u16* __restrict__ B0,
    const u16* __restrict__ A1, const u16* __restrict__ B1,
    int half_nt, int NT, int m0, int n0, u16* lds, f32x4 acc[8][4])
{
  const int tid = threadIdx.x;
  const int w = tid >> 6, lane = tid & 63;
  const int wr = w >> 2, wc = w & 3;
  const int lr = lane & 15, g = lane >> 4;

  int rc0, rc1;
  {
    int seg0 = w * 64 + lane, seg1 = 512 + w * 64 + lane;
    int L0 = swz(seg0 * 16), L1 = swz(seg1 * 16);
    rc0 = (L0 >> 6) * 1024 + ((L0 & 63) >> 1);
    rc1 = (L1 >> 6) * 1024 + ((L1 & 63) >> 1);
  }
  int aoff[8], boff[4];
  #pragma unroll
  for (int mi = 0; mi < 8; mi++)
    aoff[mi] = swz((wr * 128 + mi * 16 + lr) * 64 + g * 16);
  #pragma unroll
  for (int ni = 0; ni < 4; ni++)
    boff[ni] = swz((wc * 64 + ni * 16 + lr) * 64 + g * 16);

  short8 a0s[4], a1s[4], b0s[4], b1s[4];

  #pragma unroll
  for (int j = 0; j < 7; j++)
    stage_half(A0, B0, A1, B1, half_nt, lds, j, m0, n0, w, rc0, rc1);
  vmw<10>();
  SBAR();
  rdB4(b0s, lds, 0, 0, boff);
  rdA4(a0s, lds, 0, 0, 0, aoff);

  TILE(0, 8, -1, 8, 4, 1, 1, 1, 1, true);
  for (int t = 1; t < NT - 2; ++t)
    TILE(t, -1, -1, -1, 4, 1, 1, 1, 1, true);
  TILE(NT - 2, -1, -1, -1, 0, 1, 0, 0, 0, true);
  TILE(NT - 1, -1, -1, -1, -1, 0, 0, 0, 0, false);
}

// ---------- GEMM1: h = tanh(Q@W1^T + V@W2^T + b1 + b2), bf16 out ----------
__global__ void __launch_bounds__(512, 2)
gemm1_ker(const u16* __restrict__ q, const u16* __restrict__ v,
          const u16* __restrict__ w1, const u16* __restrict__ w2,
          const float* __restrict__ b1, const float* __restrict__ b2,
          u16* __restrict__ H)
{
  __shared__ u16 lds[65536];
  int m0, n0;
  swz_mn256(blockIdx.x, m0, n0);
  f32x4 acc[8][4];
  #pragma unroll
  for (int mi = 0; mi < 8; mi++)
    #pragma unroll
    for (int ni = 0; ni < 4; ni++) acc[mi][ni] = (f32x4){0.f, 0.f, 0.f, 0.f};

  gemm_loop(q, w1, v, w2, 16, 32, m0, n0, lds, acc);

  int tid = threadIdx.x, w = tid >> 6, lane = tid & 63;
  int wr = w >> 2, wc = w & 3, lr = lane & 15, g = lane >> 4;
  #pragma unroll
  for (int ni = 0; ni < 4; ni++) {
    int col = n0 + wc * 64 + ni * 16 + lr;
    float bias = b1[col] + b2[col];
    #pragma unroll
    for (int mi = 0; mi < 8; mi++)
      #pragma unroll
      for (int r = 0; r < 4; r++) {
        int row = m0 + wr * 128 + mi * 16 + g * 4 + r;
        H[(size_t)row * 1024 + col] = f2bf(fast_tanh(acc[mi][ni][r] + bias));
      }
  }
}

// ---------- escore: e = exp(h@Vw^T + vb) -> e_bf16 + per-(nblk,row) partial sums ----------
__global__ void __launch_bounds__(512, 2)
escore_ker(const u16* __restrict__ h, const u16* __restrict__ vw,
           const float* __restrict__ vb, u16* __restrict__ E,
           float* __restrict__ partial)
{
  __shared__ u16 lds[65536];
  int m0, n0;
  swz_mn256(blockIdx.x, m0, n0);
  f32x4 acc[8][4];
  #pragma unroll
  for (int mi = 0; mi < 8; mi++)
    #pragma unroll
    for (int ni = 0; ni < 4; ni++) acc[mi][ni] = (f32x4){0.f, 0.f, 0.f, 0.f};

  gemm_loop(h, vw, h, vw, 16, 16, m0, n0, lds, acc);

  int tid = threadIdx.x, w = tid >> 6, lane = tid & 63;
  int wr = w >> 2, wc = w & 3, lr = lane & 15, g = lane >> 4;

  // e = exp(score + vb); |score| bounded ~17 so no max-subtraction needed (fp32 safe)
  #pragma unroll
  for (int ni = 0; ni < 4; ni++) {
    float vbc = vb[n0 + wc * 64 + ni * 16 + lr];
    #pragma unroll
    for (int mi = 0; mi < 8; mi++)
      #pragma unroll
      for (int r = 0; r < 4; r++)
        acc[mi][ni][r] = __expf(acc[mi][ni][r] + vbc);
  }

  __syncthreads();            // all loop LDS traffic done before reuse as ps
  float* ps = (float*)lds;    // [wc:4][row:256], unique writer per slot
  #pragma unroll
  for (int mi = 0; mi < 8; mi++) {
    #pragma unroll
    for (int r = 0; r < 4; r++) {
      float t = acc[mi][0][r] + acc[mi][1][r] + acc[mi][2][r] + acc[mi][3][r];
      t += __shfl_xor(t, 1, 64);
      t += __shfl_xor(t, 2, 64);
      t += __shfl_xor(t, 4, 64);
      t += __shfl_xor(t, 8, 64);
      if (lr == 0) ps[wc * 256 + wr * 128 + mi * 16 + g * 4 + r] = t;
    }
  }
  __syncthreads();
  if (tid < 256) {
    float s = ps[tid] + ps[256 + tid] + ps[512 + tid] + ps[768 + tid];
    partial[(size_t)(n0 >> 8) * 32768 + m0 + tid] = s;
  }

  #pragma unroll
  for (int ni = 0; ni < 4; ni++) {
    int col = n0 + wc * 64 + ni * 16 + lr;
    #pragma unroll
    for (int mi = 0; mi < 8; mi++)
      #pragma unroll
      for (int r = 0; r < 4; r++) {
        int row = m0 + wr * 128 + mi * 16 + g * 4 + r;
        E[(size_t)row * 1024 + col] = f2bf(acc[mi][ni][r]);
      }
  }
}

// ---------- rowsum: inv[row] = 1/sum of 4 n-block partials ----------
__global__ void rowsum_ker(const float* __restrict__ partial, float* __restrict__ inv) {
  int r = blockIdx.x * 256 + threadIdx.x;
  float s = partial[r] + partial[32768 + r] + partial[65536 + r] + partial[98304 + r];
  inv[r] = 1.0f / s;
}

// ---------- wout: out_w = bf16(e) * inv[row], fp32 (standalone: r6-measured better than fusion) ----------
__global__ void wout_ker(const u16* __restrict__ E, const float* __restrict__ inv,
                         float* __restrict__ out) {
  int t = blockIdx.x * 256 + threadIdx.x;   // u16x8 chunk index; 4194304 total
  size_t base = (size_t)t * 8;
  float sc = inv[t >> 7];                    // 128 chunks per 1024-row
  u16x8 v = *(const u16x8*)(E + base);
  float4 o0, o1;
  o0.x = bf2f(v[0]) * sc; o0.y = bf2f(v[1]) * sc; o0.z = bf2f(v[2]) * sc; o0.w = bf2f(v[3]) * sc;
  o1.x = bf2f(v[4]) * sc; o1.y = bf2f(v[5]) * sc; o1.z = bf2f(v[6]) * sc; o1.w = bf2f(v[7]) * sc;
  *(float4*)(out + base) = o0;
  *(float4*)(out + base + 4) = o1;
}

// ---------- transpose v_bf per batch (fallback path): [b][l][h] -> [b][h][l] ----------
__global__ void transpose_ker(const u16* __restrict__ in, u16* __restrict__ out) {
  __shared__ u16 tile[64][68];
  int b = blockIdx.z;
  int h0 = blockIdx.x * 64, l0 = blockIdx.y * 64;
  const u16* src = in + (size_t)b * 1048576;
  u16* dst = out + (size_t)b * 1048576;
  int t = threadIdx.x;
  #pragma unroll
  for (int i = 0; i < 4; i++) {
    int idx = i * 1024 + t * 4;
    int r = idx >> 6, c = idx & 63;
    *(u16x4*)&tile[r][c] = *(const u16x4*)&src[(size_t)(l0 + r) * 1024 + h0 + c];
  }
  __syncthreads();
  #pragma unroll
  for (int i = 0; i < 4; i++) {
    int idx = i * 1024 + t * 4;
    int hr = idx >> 6, lc = idx & 63;
    u16x4 val = { tile[lc][hr], tile[lc + 1][hr], tile[lc + 2][hr], tile[lc + 3][hr] };
    *(u16x4*)&dst[(size_t)(h0 + hr) * 1024 + l0 + lc] = val;
  }
}

// ---------- GEMM3: context[b] = (e[b] @ value[b]) * inv[row] ----------
__global__ void __launch_bounds__(512, 2)
gemm3_ker(const u16* __restrict__ E, const u16* __restrict__ vT,
          const float* __restrict__ inv, float* __restrict__ ctx)
{
  __shared__ u16 lds[65536];
  int m0, n0;
  swz_mn256(blockIdx.x, m0, n0);
  const u16* Bb = vT + (size_t)(m0 >> 10) * 1048576;   // 256 | 1024: tile never straddles batches
  f32x4 acc[8][4];
  #pragma unroll
  for (int mi = 0; mi < 8; mi++)
    #pragma unroll
    for (int ni = 0; ni < 4; ni++) acc[mi][ni] = (f32x4){0.f, 0.f, 0.f, 0.f};

  gemm_loop(E, Bb, E, Bb, 16, 16, m0, n0, lds, acc);

  int tid = threadIdx.x, w = tid >> 6, lane = tid & 63;
  int wr = w >> 2, wc = w & 3, lr = lane & 15, g = lane >> 4;
  #pragma unroll
  for (int mi = 0; mi < 8; mi++) {
    #pragma unroll
    for (int r = 0; r < 4; r++) {
      int row = m0 + wr * 128 + mi * 16 + g * 4 + r;
      float sc = inv[row];
      #pragma unroll
      for (int ni = 0; ni < 4; ni++) {
        int col = n0 + wc * 64 + ni * 16 + lr;
        ctx[(size_t)row * 1024 + col] = acc[mi][ni][r] * sc;
      }
    }
  }
}

// ---------- launch ----------
extern "C" void kernel_launch(void* const* d_in, const int* in_sizes, int n_in,
                              void* d_out, int out_size, void* d_ws, size_t ws_size,
                              hipStream_t stream) {
  const float* q   = (const float*)d_in[0];
  // d_in[1] = key, unused by reference
  const float* v   = (const float*)d_in[2];
  const float* w1w = (const float*)d_in[3];
  const float* b1  = (const float*)d_in[4];
  const float* w2w = (const float*)d_in[5];
  const float* b2  = (const float*)d_in[6];
  const float* vww = (const float*)d_in[7];
  const float* vb  = (const float*)d_in[8];

  float* out_w = (float*)d_out;                 // attention_weights (32,1024,1024) fp32
  float* out_c = out_w + (size_t)33554432;      // context          (32,1024,1024) fp32

  u16* q_bf  = (u16*)d_ws;
  u16* v_bf  = q_bf + 33554432;
  u16* h_bf  = v_bf + 33554432;
  u16* w1_bf = h_bf + 33554432;
  u16* w2_bf = w1_bf + 1048576;
  u16* vw_bf = w2_bf + 1048576;
  u16* wsm_bf = q_bf;                   // e bf16: reuse q region (dead after gemm1)
  float* partial = (float*)w1_bf;       // 512 KB (w1 dead after gemm1)
  float* invp    = (float*)w2_bf;       // 128 KB (w2 dead after gemm1)

  if (ws_size < (size_t)207618048) return;  // minimum layout

  // big-ws path: dedicated vT region lets V-cvt + transpose fuse into one pass
  const bool bigws = ws_size >= (size_t)274726912;
  u16* vT_big = vw_bf + 1048576;        // +64 MB region (only if bigws)
  u16* vT_bf  = bigws ? vT_big : h_bf;  // fallback: h region (dead after escore)

  cvt_ker<<<32768, 256, 0, stream>>>((const float4*)q, (u16x4*)q_bf, 8388608);
  if (bigws) {
    vcvtT_ker<<<dim3(16, 16, 32), 256, 0, stream>>>(v, v_bf, vT_big);
  } else {
    cvt_ker<<<32768, 256, 0, stream>>>((const float4*)v, (u16x4*)v_bf, 8388608);
  }
  wcvt_ker<<<dim3(1024, 3), 256, 0, stream>>>(
      (const float4*)w1w, (const float4*)w2w, (const float4*)vww,
      (u16x4*)w1_bf, (u16x4*)w2_bf, (u16x4*)vw_bf);

  gemm1_ker<<<512, 512, 0, stream>>>(q_bf, v_bf, w1_bf, w2_bf, b1, b2, h_bf);
  escore_ker<<<512, 512, 0, stream>>>(h_bf, vw_bf, vb, wsm_bf, partial);
  rowsum_ker<<<128, 256, 0, stream>>>(partial, invp);
  if (!bigws)
    transpose_ker<<<dim3(16, 16, 32), 256, 0, stream>>>(v_bf, vT_bf);
  wout_ker<<<16384, 256, 0, stream>>>(wsm_bf, invp, out_w);
  gemm3_ker<<<512, 512, 0, stream>>>(wsm_bf, vT_bf, invp, out_c);
}

// Round 11
// 439.667 us; speedup vs baseline: 1.0541x; 1.0019x over previous
//
#include <hip/hip_runtime.h>
#include <cstdint>

using u16 = unsigned short;
using u32 = unsigned int;
typedef __attribute__((ext_vector_type(4))) float f32x4;
typedef __attribute__((ext_vector_type(8))) short short8;
typedef __attribute__((ext_vector_type(4))) u16 u16x4;
typedef __attribute__((ext_vector_type(8))) u16 u16x8;

// ---------- helpers ----------
__device__ __forceinline__ u16 f2bf(float f) {
  u32 u = __builtin_bit_cast(u32, f);
  u += 0x7FFFu + ((u >> 16) & 1u);
  return (u16)(u >> 16);
}
__device__ __forceinline__ float bf2f(u16 x) {
  return __builtin_bit_cast(float, (u32)x << 16);
}

__device__ __forceinline__ void gload16(const void* g, void* l) {
  __builtin_amdgcn_global_load_lds(
      (const __attribute__((address_space(1))) void*)g,
      (__attribute__((address_space(3))) void*)l, 16, 0, 0);
}

__device__ __forceinline__ float fast_tanh(float x) {
  float ax = fabsf(x);
  float e = __expf(-2.0f * ax);
  float r = (1.0f - e) / (1.0f + e);
  return x < 0.0f ? -r : r;
}

#define SBAR() do { asm volatile("" ::: "memory"); __builtin_amdgcn_s_barrier(); asm volatile("" ::: "memory"); } while (0)

template<int N> __device__ __forceinline__ void vmw() {
  if constexpr (N == 10) asm volatile("s_waitcnt vmcnt(10)" ::: "memory");
  else if constexpr (N == 8) asm volatile("s_waitcnt vmcnt(8)" ::: "memory");
  else if constexpr (N == 6) asm volatile("s_waitcnt vmcnt(6)" ::: "memory");
  else if constexpr (N == 4) asm volatile("s_waitcnt vmcnt(4)" ::: "memory");
  else if constexpr (N == 2) asm volatile("s_waitcnt vmcnt(2)" ::: "memory");
  else if constexpr (N == 0) asm volatile("s_waitcnt vmcnt(0)" ::: "memory");
  // N == -1: no wait
}

// st_16x32 XOR swizzle on a byte offset within a 16 KiB half-tile
__device__ __forceinline__ int swz(int L) { return L ^ (((L >> 9) & 1) << 5); }

// XCD-aware swizzle for 512 blocks (128 m-tiles x 4 n-tiles of 256)
__device__ __forceinline__ void swz_mn256(int bid, int& m0, int& n0) {
  int s = (bid & 7) * 64 + (bid >> 3);
  n0 = (s & 3) << 8;
  m0 = (s >> 2) << 8;
}

// ---------- fp32 -> bf16 convert ----------
__global__ void cvt_ker(const float4* __restrict__ src, u16x4* __restrict__ dst, int n4) {
  int i = blockIdx.x * 256 + threadIdx.x;
  if (i < n4) {
    float4 f = src[i];
    u16x4 o = { f2bf(f.x), f2bf(f.y), f2bf(f.z), f2bf(f.w) };
    dst[i] = o;
  }
}

// ---------- merged weight cvt: y selects among w1,w2,vw (each 1M f32) ----------
__global__ void wcvt_ker(const float4* __restrict__ w1, const float4* __restrict__ w2,
                         const float4* __restrict__ vw, u16x4* __restrict__ d1,
                         u16x4* __restrict__ d2, u16x4* __restrict__ d3) {
  int i = blockIdx.x * 256 + threadIdx.x;   // 262144 float4 per matrix
  const float4* s = blockIdx.y == 0 ? w1 : blockIdx.y == 1 ? w2 : vw;
  u16x4* d = blockIdx.y == 0 ? d1 : blockIdx.y == 1 ? d2 : d3;
  float4 f = s[i];
  u16x4 o = { f2bf(f.x), f2bf(f.y), f2bf(f.z), f2bf(f.w) };
  d[i] = o;
}

// ---------- fused V cvt + transpose (big-ws path): f32 [b][l][h] -> bf16 [b][l][h] AND [b][h][l] ----------
__global__ void vcvtT_ker(const float* __restrict__ src, u16* __restrict__ v_bf,
                          u16* __restrict__ vT) {
  __shared__ u16 tile[64][68];   // 68: keeps u16x4 8B-aligned, breaks bank stride
  int b = blockIdx.z;
  int h0 = blockIdx.x * 64, l0 = blockIdx.y * 64;
  const float* s = src + (size_t)b * 1048576;
  u16* dv = v_bf + (size_t)b * 1048576;
  u16* dt = vT + (size_t)b * 1048576;
  int t = threadIdx.x;
  #pragma unroll
  for (int i = 0; i < 4; i++) {
    int idx = i * 1024 + t * 4;
    int r = idx >> 6, c = idx & 63;
    float4 f = *(const float4*)&s[(size_t)(l0 + r) * 1024 + h0 + c];
    tile[r][c] = f2bf(f.x); tile[r][c + 1] = f2bf(f.y);
    tile[r][c + 2] = f2bf(f.z); tile[r][c + 3] = f2bf(f.w);
  }
  __syncthreads();
  #pragma unroll
  for (int i = 0; i < 4; i++) {
    int idx = i * 1024 + t * 4;
    int r = idx >> 6, c = idx & 63;
    *(u16x4*)&dv[(size_t)(l0 + r) * 1024 + h0 + c] = *(const u16x4*)&tile[r][c];
  }
  #pragma unroll
  for (int i = 0; i < 4; i++) {
    int idx = i * 1024 + t * 4;
    int hr = idx >> 6, lc = idx & 63;
    u16x4 val = { tile[lc][hr], tile[lc + 1][hr], tile[lc + 2][hr], tile[lc + 3][hr] };
    *(u16x4*)&dt[(size_t)(h0 + hr) * 1024 + l0 + lc] = val;
  }
}

// ---------- 256x256 GEMM mainloop, BK=64, pipelined ds_reads, 2 BARRIERS/TILE ----------
// C[m][n] += sum_k A[m][k]*B[n][k], bf16 BT-form, K tiles of 64. 8 waves (2x4).
// LDS 128 KiB: [buf:2][half:4][8192]; half 0=B.kk0 1=A.kk0 2=B.kk1 3=A.kk1.
// Stage stream S[j]: prologue S[0..6]; phase G stages S[G+7].
// LEDGER (steady tiles, barriers at P1/P3 end only; vmcnt(2) at P3):
//  reads: tile t touches S[4t..4t+3] + pre-reads S[4t+4],S[4t+5]; P3(t-1) vmcnt(2)
//         -> complete <= S[4(t-1)+9] = S[4t+5]  => ALL covered, exactly.  [counted]
//  overwrites: S[4t+7]/S[4t+8] last-old-read at P2(t-1)/P3(t-1), barrier P3(t-1)-end;
//         S[4t+9]/S[4t+10] last-old-read at P0(t)/P1(t), barrier P1(t)-end.  [ordered]
//  tile 0 keeps 4 barriers (prologue-drain cross-wave visibility); tile NT-1 none.
__device__ __forceinline__ void stage_half(
    const u16* __restrict__ A0, const u16* __restrict__ B0,
    const u16* __restrict__ A1, const u16* __restrict__ B1,
    int half_nt, u16* lds, int j, int m0, int n0, int w, int rc0, int rc1)
{
  int jt = j >> 2, hh = j & 3;
  int kk = hh >> 1, isA = hh & 1;
  const u16* src;
  int kt;
  if (jt < half_nt) { src = isA ? A0 : B0; kt = jt; }
  else              { src = isA ? A1 : B1; kt = jt - half_nt; }
  int base_row = isA ? m0 : n0;
  int koff = kt * 64 + kk * 32;
  u16* dst = lds + ((jt & 1) * 4 + hh) * 8192 + w * 512;
  const u16* g0 = src + (size_t)base_row * 1024 + koff;
  gload16(g0 + rc0, dst);
  gload16(g0 + rc1, dst + 4096);
}

__device__ __forceinline__ void rdB4(short8* d, const u16* lds, int buf, int kk, const int* boff) {
  const char* h = (const char*)(lds + (buf * 4 + kk * 2) * 8192);
  d[0] = *(const short8*)(h + boff[0]);
  d[1] = *(const short8*)(h + boff[1]);
  d[2] = *(const short8*)(h + boff[2]);
  d[3] = *(const short8*)(h + boff[3]);
}
__device__ __forceinline__ void rdA4(short8* d, const u16* lds, int buf, int kk, int mh, const int* aoff) {
  const char* h = (const char*)(lds + (buf * 4 + 1 + kk * 2) * 8192);
  d[0] = *(const short8*)(h + aoff[mh * 4 + 0]);
  d[1] = *(const short8*)(h + aoff[mh * 4 + 1]);
  d[2] = *(const short8*)(h + aoff[mh * 4 + 2]);
  d[3] = *(const short8*)(h + aoff[mh * 4 + 3]);
}

#define MFMA16(AS, BS, BASE) do {                                                   \
  __builtin_amdgcn_s_setprio(1);                                                    \
  _Pragma("unroll")                                                                 \
  for (int ni_ = 0; ni_ < 4; ni_++) {                                               \
    acc[(BASE)+0][ni_] = __builtin_amdgcn_mfma_f32_16x16x32_bf16(AS[0], BS[ni_], acc[(BASE)+0][ni_], 0, 0, 0); \
    acc[(BASE)+1][ni_] = __builtin_amdgcn_mfma_f32_16x16x32_bf16(AS[1], BS[ni_], acc[(BASE)+1][ni_], 0, 0, 0); \
    acc[(BASE)+2][ni_] = __builtin_amdgcn_mfma_f32_16x16x32_bf16(AS[2], BS[ni_], acc[(BASE)+2][ni_], 0, 0, 0); \
    acc[(BASE)+3][ni_] = __builtin_amdgcn_mfma_f32_16x16x32_bf16(AS[3], BS[ni_], acc[(BASE)+3][ni_], 0, 0, 0); \
  }                                                                                 \
  __builtin_amdgcn_s_setprio(0);                                                    \
} while (0)

// One K-tile = 4 phases; per-phase barrier now OPTIONAL (B0..B3 flags).
#define TILE(T, V0, V1, V2, V3, S0_, S1_, S2_, S3_, NX, B0_, B1_, B2_, B3_) do {    \
  const int buf_ = (T) & 1;                                                         \
  /* P0: mfma(kk0,mh0); read a1s = A.mh1.kk0 */                                     \
  rdA4(a1s, lds, buf_, 0, 1, aoff);                                                 \
  if (S0_) stage_half(A0, B0, A1, B1, half_nt, lds, 4 * (T) + 7, m0, n0, w, rc0, rc1); \
  MFMA16(a0s, b0s, 0);                                                              \
  vmw<V0>(); if (B0_) SBAR();                                                       \
  /* P1: mfma(kk0,mh1); read b1s = B.kk1, a0s = A.mh0.kk1 */                        \
  rdB4(b1s, lds, buf_, 1, boff);                                                    \
  rdA4(a0s, lds, buf_, 1, 0, aoff);                                                 \
  if (S1_) stage_half(A0, B0, A1, B1, half_nt, lds, 4 * (T) + 8, m0, n0, w, rc0, rc1); \
  MFMA16(a1s, b0s, 4);                                                              \
  vmw<V1>(); if (B1_) SBAR();                                                       \
  /* P2: mfma(kk1,mh0); read a1s = A.mh1.kk1 */                                     \
  rdA4(a1s, lds, buf_, 1, 1, aoff);                                                 \
  if (S2_) stage_half(A0, B0, A1, B1, half_nt, lds, 4 * (T) + 9, m0, n0, w, rc0, rc1); \
  MFMA16(a0s, b1s, 0);                                                              \
  vmw<V2>(); if (B2_) SBAR();                                                       \
  /* P3: mfma(kk1,mh1); pre-read next tile's b0s/a0s */                             \
  if (NX) { rdB4(b0s, lds, buf_ ^ 1, 0, boff); rdA4(a0s, lds, buf_ ^ 1, 0, 0, aoff); } \
  if (S3_) stage_half(A0, B0, A1, B1, half_nt, lds, 4 * (T) + 10, m0, n0, w, rc0, rc1); \
  MFMA16(a1s, b1s, 4);                                                              \
  vmw<V3>(); if (B3_) SBAR();                                                       \
} while (0)

__device__ __forceinline__ void gemm_loop(
    const u16* __restrict__ A0, const u16* __restrict__ B0,
    const u16* __restrict__ A1, const u16* __restrict__ B1,
    int half_nt, int NT, int m0, int n0, u16* lds, f32x4 acc[8][4])
{
  const int tid = threadIdx.x;
  const int w = tid >> 6, lane = tid & 63;
  const int wr = w >> 2, wc = w & 3;
  const int lr = lane & 15, g = lane >> 4;

  int rc0, rc1;
  {
    int seg0 = w * 64 + lane, seg1 = 512 + w * 64 + lane;
    int L0 = swz(seg0 * 16), L1 = swz(seg1 * 16);
    rc0 = (L0 >> 6) * 1024 + ((L0 & 63) >> 1);
    rc1 = (L1 >> 6) * 1024 + ((L1 & 63) >> 1);
  }
  int aoff[8], boff[4];
  #pragma unroll
  for (int mi = 0; mi < 8; mi++)
    aoff[mi] = swz((wr * 128 + mi * 16 + lr) * 64 + g * 16);
  #pragma unroll
  for (int ni = 0; ni < 4; ni++)
    boff[ni] = swz((wc * 64 + ni * 16 + lr) * 64 + g * 16);

  short8 a0s[4], a1s[4], b0s[4], b1s[4];

  #pragma unroll
  for (int j = 0; j < 7; j++)
    stage_half(A0, B0, A1, B1, half_nt, lds, j, m0, n0, w, rc0, rc1);
  vmw<10>();
  SBAR();
  rdB4(b0s, lds, 0, 0, boff);
  rdA4(a0s, lds, 0, 0, 0, aoff);

  // tile 0: 4 barriers (prologue-drain cross-wave visibility) + counted vmcnt
  TILE(0, 8, -1, 8, 2, 1, 1, 1, 1, true, 1, 1, 1, 1);
  // steady: barriers at P1/P3 only, vmcnt(2) at P3 (counted ledger above)
  for (int t = 1; t < NT - 2; ++t)
    TILE(t, -1, -1, -1, 2, 1, 1, 1, 1, true, 0, 1, 0, 1);
  TILE(NT - 2, -1, -1, -1, 0, 1, 0, 0, 0, true, 0, 1, 0, 1);
  TILE(NT - 1, -1, -1, -1, -1, 0, 0, 0, 0, false, 0, 0, 0, 0);
}

// ---------- GEMM1: h = tanh(Q@W1^T + V@W2^T + b1 + b2), bf16 out ----------
__global__ void __launch_bounds__(512, 2)
gemm1_ker(const u16* __restrict__ q, const u16* __restrict__ v,
          const u16* __restrict__ w1, const u16* __restrict__ w2,
          const float* __restrict__ b1, const float* __restrict__ b2,
          u16* __restrict__ H)
{
  __shared__ u16 lds[65536];
  int m0, n0;
  swz_mn256(blockIdx.x, m0, n0);
  f32x4 acc[8][4];
  #pragma unroll
  for (int mi = 0; mi < 8; mi++)
    #pragma unroll
    for (int ni = 0; ni < 4; ni++) acc[mi][ni] = (f32x4){0.f, 0.f, 0.f, 0.f};

  gemm_loop(q, w1, v, w2, 16, 32, m0, n0, lds, acc);

  int tid = threadIdx.x, w = tid >> 6, lane = tid & 63;
  int wr = w >> 2, wc = w & 3, lr = lane & 15, g = lane >> 4;
  #pragma unroll
  for (int ni = 0; ni < 4; ni++) {
    int col = n0 + wc * 64 + ni * 16 + lr;
    float bias = b1[col] + b2[col];
    #pragma unroll
    for (int mi = 0; mi < 8; mi++)
      #pragma unroll
      for (int r = 0; r < 4; r++) {
        int row = m0 + wr * 128 + mi * 16 + g * 4 + r;
        H[(size_t)row * 1024 + col] = f2bf(fast_tanh(acc[mi][ni][r] + bias));
      }
  }
}

// ---------- escore: e = exp(h@Vw^T + vb) -> e_bf16 + per-(nblk,row) partial sums ----------
__global__ void __launch_bounds__(512, 2)
escore_ker(const u16* __restrict__ h, const u16* __restrict__ vw,
           const float* __restrict__ vb, u16* __restrict__ E,
           float* __restrict__ partial)
{
  __shared__ u16 lds[65536];
  int m0, n0;
  swz_mn256(blockIdx.x, m0, n0);
  f32x4 acc[8][4];
  #pragma unroll
  for (int mi = 0; mi < 8; mi++)
    #pragma unroll
    for (int ni = 0; ni < 4; ni++) acc[mi][ni] = (f32x4){0.f, 0.f, 0.f, 0.f};

  gemm_loop(h, vw, h, vw, 16, 16, m0, n0, lds, acc);

  int tid = threadIdx.x, w = tid >> 6, lane = tid & 63;
  int wr = w >> 2, wc = w & 3, lr = lane & 15, g = lane >> 4;

  // e = exp(score + vb); |score| bounded ~17 so no max-subtraction needed (fp32 safe)
  #pragma unroll
  for (int ni = 0; ni < 4; ni++) {
    float vbc = vb[n0 + wc * 64 + ni * 16 + lr];
    #pragma unroll
    for (int mi = 0; mi < 8; mi++)
      #pragma unroll
      for (int r = 0; r < 4; r++)
        acc[mi][ni][r] = __expf(acc[mi][ni][r] + vbc);
  }

  __syncthreads();            // all loop LDS traffic done before reuse as ps
  float* ps = (float*)lds;    // [wc:4][row:256], unique writer per slot
  #pragma unroll
  for (int mi = 0; mi < 8; mi++) {
    #pragma unroll
    for (int r = 0; r < 4; r++) {
      float t = acc[mi][0][r] + acc[mi][1][r] + acc[mi][2][r] + acc[mi][3][r];
      t += __shfl_xor(t, 1, 64);
      t += __shfl_xor(t, 2, 64);
      t += __shfl_xor(t, 4, 64);
      t += __shfl_xor(t, 8, 64);
      if (lr == 0) ps[wc * 256 + wr * 128 + mi * 16 + g * 4 + r] = t;
    }
  }
  __syncthreads();
  if (tid < 256) {
    float s = ps[tid] + ps[256 + tid] + ps[512 + tid] + ps[768 + tid];
    partial[(size_t)(n0 >> 8) * 32768 + m0 + tid] = s;
  }

  #pragma unroll
  for (int ni = 0; ni < 4; ni++) {
    int col = n0 + wc * 64 + ni * 16 + lr;
    #pragma unroll
    for (int mi = 0; mi < 8; mi++)
      #pragma unroll
      for (int r = 0; r < 4; r++) {
        int row = m0 + wr * 128 + mi * 16 + g * 4 + r;
        E[(size_t)row * 1024 + col] = f2bf(acc[mi][ni][r]);
      }
  }
}

// ---------- rowsum: inv[row] = 1/sum of 4 n-block partials ----------
__global__ void rowsum_ker(const float* __restrict__ partial, float* __restrict__ inv) {
  int r = blockIdx.x * 256 + threadIdx.x;
  float s = partial[r] + partial[32768 + r] + partial[65536 + r] + partial[98304 + r];
  inv[r] = 1.0f / s;
}

// ---------- wout: out_w = bf16(e) * inv[row], fp32 ----------
__global__ void wout_ker(const u16* __restrict__ E, const float* __restrict__ inv,
                         float* __restrict__ out) {
  int t = blockIdx.x * 256 + threadIdx.x;   // u16x8 chunk index; 4194304 total
  size_t base = (size_t)t * 8;
  float sc = inv[t >> 7];                    // 128 chunks per 1024-row
  u16x8 v = *(const u16x8*)(E + base);
  float4 o0, o1;
  o0.x = bf2f(v[0]) * sc; o0.y = bf2f(v[1]) * sc; o0.z = bf2f(v[2]) * sc; o0.w = bf2f(v[3]) * sc;
  o1.x = bf2f(v[4]) * sc; o1.y = bf2f(v[5]) * sc; o1.z = bf2f(v[6]) * sc; o1.w = bf2f(v[7]) * sc;
  *(float4*)(out + base) = o0;
  *(float4*)(out + base + 4) = o1;
}

// ---------- transpose v_bf per batch (fallback path): [b][l][h] -> [b][h][l] ----------
__global__ void transpose_ker(const u16* __restrict__ in, u16* __restrict__ out) {
  __shared__ u16 tile[64][68];
  int b = blockIdx.z;
  int h0 = blockIdx.x * 64, l0 = blockIdx.y * 64;
  const u16* src = in + (size_t)b * 1048576;
  u16* dst = out + (size_t)b * 1048576;
  int t = threadIdx.x;
  #pragma unroll
  for (int i = 0; i < 4; i++) {
    int idx = i * 1024 + t * 4;
    int r = idx >> 6, c = idx & 63;
    *(u16x4*)&tile[r][c] = *(const u16x4*)&src[(size_t)(l0 + r) * 1024 + h0 + c];
  }
  __syncthreads();
  #pragma unroll
  for (int i = 0; i < 4; i++) {
    int idx = i * 1024 + t * 4;
    int hr = idx >> 6, lc = idx & 63;
    u16x4 val = { tile[lc][hr], tile[lc + 1][hr], tile[lc + 2][hr], tile[lc + 3][hr] };
    *(u16x4*)&dst[(size_t)(h0 + hr) * 1024 + l0 + lc] = val;
  }
}

// ---------- GEMM3: context[b] = (e[b] @ value[b]) * inv[row] ----------
__global__ void __launch_bounds__(512, 2)
gemm3_ker(const u16* __restrict__ E, const u16* __restrict__ vT,
          const float* __restrict__ inv, float* __restrict__ ctx)
{
  __shared__ u16 lds[65536];
  int m0, n0;
  swz_mn256(blockIdx.x, m0, n0);
  const u16* Bb = vT + (size_t)(m0 >> 10) * 1048576;   // 256 | 1024: tile never straddles batches
  f32x4 acc[8][4];
  #pragma unroll
  for (int mi = 0; mi < 8; mi++)
    #pragma unroll
    for (int ni = 0; ni < 4; ni++) acc[mi][ni] = (f32x4){0.f, 0.f, 0.f, 0.f};

  gemm_loop(E, Bb, E, Bb, 16, 16, m0, n0, lds, acc);

  int tid = threadIdx.x, w = tid >> 6, lane = tid & 63;
  int wr = w >> 2, wc = w & 3, lr = lane & 15, g = lane >> 4;
  #pragma unroll
  for (int mi = 0; mi < 8; mi++) {
    #pragma unroll
    for (int r = 0; r < 4; r++) {
      int row = m0 + wr * 128 + mi * 16 + g * 4 + r;
      float sc = inv[row];
      #pragma unroll
      for (int ni = 0; ni < 4; ni++) {
        int col = n0 + wc * 64 + ni * 16 + lr;
        ctx[(size_t)row * 1024 + col] = acc[mi][ni][r] * sc;
      }
    }
  }
}

// ---------- launch ----------
extern "C" void kernel_launch(void* const* d_in, const int* in_sizes, int n_in,
                              void* d_out, int out_size, void* d_ws, size_t ws_size,
                              hipStream_t stream) {
  const float* q   = (const float*)d_in[0];
  // d_in[1] = key, unused by reference
  const float* v   = (const float*)d_in[2];
  const float* w1w = (const float*)d_in[3];
  const float* b1  = (const float*)d_in[4];
  const float* w2w = (const float*)d_in[5];
  const float* b2  = (const float*)d_in[6];
  const float* vww = (const float*)d_in[7];
  const float* vb  = (const float*)d_in[8];

  float* out_w = (float*)d_out;                 // attention_weights (32,1024,1024) fp32
  float* out_c = out_w + (size_t)33554432;      // context          (32,1024,1024) fp32

  u16* q_bf  = (u16*)d_ws;
  u16* v_bf  = q_bf + 33554432;
  u16* h_bf  = v_bf + 33554432;
  u16* w1_bf = h_bf + 33554432;
  u16* w2_bf = w1_bf + 1048576;
  u16* vw_bf = w2_bf + 1048576;
  u16* wsm_bf = q_bf;                   // e bf16: reuse q region (dead after gemm1)
  float* partial = (float*)w1_bf;       // 512 KB (w1 dead after gemm1)
  float* invp    = (float*)w2_bf;       // 128 KB (w2 dead after gemm1)

  if (ws_size < (size_t)207618048) return;  // minimum layout

  // big-ws path: dedicated vT region lets V-cvt + transpose fuse into one pass
  const bool bigws = ws_size >= (size_t)274726912;
  u16* vT_big = vw_bf + 1048576;        // +64 MB region (only if bigws)
  u16* vT_bf  = bigws ? vT_big : h_bf;  // fallback: h region (dead after escore)

  cvt_ker<<<32768, 256, 0, stream>>>((const float4*)q, (u16x4*)q_bf, 8388608);
  if (bigws) {
    vcvtT_ker<<<dim3(16, 16, 32), 256, 0, stream>>>(v, v_bf, vT_big);
  } else {
    cvt_ker<<<32768, 256, 0, stream>>>((const float4*)v, (u16x4*)v_bf, 8388608);
  }
  wcvt_ker<<<dim3(1024, 3), 256, 0, stream>>>(
      (const float4*)w1w, (const float4*)w2w, (const float4*)vww,
      (u16x4*)w1_bf, (u16x4*)w2_bf, (u16x4*)vw_bf);

  gemm1_ker<<<512, 512, 0, stream>>>(q_bf, v_bf, w1_bf, w2_bf, b1, b2, h_bf);
  escore_ker<<<512, 512, 0, stream>>>(h_bf, vw_bf, vb, wsm_bf, partial);
  rowsum_ker<<<128, 256, 0, stream>>>(partial, invp);
  if (!bigws)
    transpose_ker<<<dim3(16, 16, 32), 256, 0, stream>>>(v_bf, vT_bf);
  wout_ker<<<16384, 256, 0, stream>>>(wsm_bf, invp, out_w);
  gemm3_ker<<<512, 512, 0, stream>>>(wsm_bf, vT_bf, invp, out_c);
}